// Round 3
// baseline (8638.403 us; speedup 1.0000x reference)
//
#include <hip/hip_runtime.h>
#include <stdint.h>

#define BATCH 256
#define SEQT  512
#define INSZ  256
#define HID   512

typedef __attribute__((ext_vector_type(8))) short short8;
typedef __attribute__((ext_vector_type(4))) float floatx4;
typedef __attribute__((ext_vector_type(2))) float floatx2;
typedef __attribute__((ext_vector_type(4))) float float4v;

__device__ __forceinline__ ushort f2b(float f) {
    union { float f; uint i; } v; v.f = f;
    uint r = (v.i + 0x7FFFu + ((v.i >> 16) & 1u)) >> 16;
    return (ushort)r;
}
__device__ __forceinline__ float fsigmoid(float x) {
    float e = __builtin_amdgcn_exp2f(-1.44269504f * x);
    return __builtin_amdgcn_rcpf(1.0f + e);
}
__device__ __forceinline__ float ftanh(float x) {
    float e = __builtin_amdgcn_exp2f(-2.88539008f * x);
    return 2.0f * __builtin_amdgcn_rcpf(1.0f + e) - 1.0f;
}

// Convert x fp32 -> bf16, same [B][T][I] layout. 4 elements/thread.
__global__ __launch_bounds__(256) void pack_x(
    const float4v* __restrict__ x, ushort* __restrict__ xp)
{
    uint idx = blockIdx.x * 256u + threadIdx.x;
    float4v v = x[idx];
    ushort4 o;
    o.x = f2b(v[0]); o.y = f2b(v[1]); o.z = f2b(v[2]); o.w = f2b(v[3]);
    *(ushort4*)&xp[idx * 4u] = o;
}

// Pack the 8 fp32 weight matrices into bf16 MFMA B-fragment layout.
// Wh per gate q: [c16(32)][k8(64)][n(16)][j(8)]  value = W[k8*8+j][c16*16+n]
// Wu per gate q: [c16(32)][k8(32)][n(16)][j(8)]
__global__ __launch_bounds__(256) void pack_weights(
    const float* __restrict__ whi, const float* __restrict__ whf,
    const float* __restrict__ whg, const float* __restrict__ who,
    const float* __restrict__ wui, const float* __restrict__ wuf,
    const float* __restrict__ wug, const float* __restrict__ wuo,
    ushort* __restrict__ whp, ushort* __restrict__ wup)
{
    uint idx = blockIdx.x * 256u + threadIdx.x;
    if (idx < (1u << 20)) {
        uint n = idx & 15u, j = (idx >> 4) & 7u;
        uint k8 = (idx >> 7) & 63u, c16 = (idx >> 13) & 31u, q = idx >> 18;
        const float* w = (q == 0) ? whi : (q == 1) ? whf : (q == 2) ? whg : who;
        float v = w[(k8 * 8u + j) * HID + c16 * 16u + n];
        whp[(((q * 32u + c16) * 64u + k8) * 16u + n) * 8u + j] = f2b(v);
    } else {
        uint idx2 = idx - (1u << 20);
        if (idx2 < (1u << 19)) {
            uint n = idx2 & 15u, j = (idx2 >> 4) & 7u;
            uint k8 = (idx2 >> 7) & 31u, c16 = (idx2 >> 12) & 31u, q = idx2 >> 17;
            const float* w = (q == 0) ? wui : (q == 1) ? wuf : (q == 2) ? wug : wuo;
            float v = w[(k8 * 8u + j) * HID + c16 * 16u + n];
            wup[(((q * 32u + c16) * 32u + k8) * 16u + n) * 8u + j] = f2b(v);
        }
    }
}

// Persistent LSTM: 256 blocks (= #CUs), one launch for all 512 steps.
// Block (rg 0..15 batch-group of 16 rows, ug 0..15 unit-group of 32 units).
// Wave = gate (4 waves). Weights live in VGPRs for the whole kernel.
// Cliques of 16 blocks (same rg) sync via per-block step flags (agent atomics).
__global__ __launch_bounds__(256, 1) void lstm_persist(
    const short8* __restrict__ xp,   // [B][T][I] bf16 as short8
    const short8* __restrict__ whp,  // packed, q-stride 32768 (short8)
    const short8* __restrict__ wup,  // packed, q-stride 16384 (short8)
    const float* __restrict__ bi, const float* __restrict__ bfr,
    const float* __restrict__ bg, const float* __restrict__ bo,
    ushort* __restrict__ h0b,        // h ping  [k8(64)][b(256)] short8
    ushort* __restrict__ h1b,        // h pong
    uint*   __restrict__ flags,      // [256] steps completed per block
    float* __restrict__ out)
{
    __shared__ short8 hstage[1088];       // [k8(64)] stride 17 [b(16)]
    __shared__ float  gtile[4 * 16 * 34]; // [gate][b_local(16)][u_local(32) pad->34]

    const uint blk = blockIdx.x;
    const uint rg = blk >> 4, ug = blk & 15u;
    const uint bbase = rg * 16u;
    const uint tid = threadIdx.x;
    const uint lane = tid & 63u;
    const uint q = tid >> 6;              // gate index = wave
    const uint m = lane & 15u, quad = lane >> 4;
    const uint b_row = bbase + m;

    // ---- weights -> registers (once) ----
    short8 wH[16][2];
    short8 wX[8][2];
    {
        const uint qh = q * 32768u, qx = q * 16384u;
        #pragma unroll
        for (int it = 0; it < 16; ++it) {
            uint k8 = (uint)it * 4u + quad;
            #pragma unroll
            for (int s = 0; s < 2; ++s) {
                uint c16 = ug * 2u + (uint)s;
                wH[it][s] = whp[qh + (c16 * 64u + k8) * 16u + m];
            }
        }
        #pragma unroll
        for (int kx = 0; kx < 8; ++kx) {
            #pragma unroll
            for (int s = 0; s < 2; ++s) {
                uint c16 = ug * 2u + (uint)s;
                wX[kx][s] = wup[qx + (c16 * 32u + (uint)kx * 4u + quad) * 16u + m];
            }
        }
    }

    // ---- epilogue ownership: 2 elements per thread ----
    const uint eb = tid & 15u;            // local batch row
    const uint eu = (tid >> 4) * 2u;      // local unit (even)
    const uint gb = bbase + eb;           // global batch row
    const uint gu = ug * 32u + eu;        // global unit
    float c0 = 0.f, c1 = 0.f;
    const float vbi0 = bi[gu],  vbi1 = bi[gu + 1];
    const float vbf0 = bfr[gu], vbf1 = bfr[gu + 1];
    const float vbg0 = bg[gu],  vbg1 = bg[gu + 1];
    const float vbo0 = bo[gu],  vbo1 = bo[gu + 1];
    const uint hidx = (((gu >> 3) * 256u + gb) * 8u + (gu & 7u)) >> 1; // uint idx

    // ---- x prefetch for t=0 ----
    short8 xa[8];
    #pragma unroll
    for (int kx = 0; kx < 8; ++kx)
        xa[kx] = xp[(b_row * SEQT + 0u) * 32u + (uint)kx * 4u + quad];

    const uint flagbase = rg * 16u;

    for (int t = 0; t < SEQT; ++t) {
        // x-path MFMAs (independent of h -> before the barrier)
        floatx4 acc0 = {}, acc1 = {};
        #pragma unroll
        for (int kx = 0; kx < 8; ++kx) {
            acc0 = __builtin_amdgcn_mfma_f32_16x16x32_bf16(xa[kx], wX[kx][0], acc0, 0, 0, 0);
            acc1 = __builtin_amdgcn_mfma_f32_16x16x32_bf16(xa[kx], wX[kx][1], acc1, 0, 0, 0);
        }
        // prefetch x for t+1 (hides in the spin)
        short8 xn[8];
        {
            uint tn = (t + 1 < SEQT) ? (uint)(t + 1) : (uint)t;
            #pragma unroll
            for (int kx = 0; kx < 8; ++kx)
                xn[kx] = xp[(b_row * SEQT + tn) * 32u + (uint)kx * 4u + quad];
        }
        // clique barrier: wait until all 16 peer blocks completed step t-1
        if (t > 0) {
            for (;;) {
                uint v = 0xFFFFFFFFu;
                if (lane < 16u)
                    v = __hip_atomic_load(&flags[flagbase + lane],
                                          __ATOMIC_RELAXED, __HIP_MEMORY_SCOPE_AGENT);
                if (__ballot(v < (uint)t) == 0ull) break;
                __builtin_amdgcn_s_sleep(1);
            }
            __builtin_amdgcn_fence(__ATOMIC_ACQUIRE, "agent");
        }
        // stage this block's h slice (16 rows x 512 units = 16 KB) into LDS
        {
            const short8* hin = (const short8*)((t & 1) ? h1b : h0b);
            #pragma unroll
            for (int i = 0; i < 4; ++i) {
                uint c = (uint)i * 256u + tid;      // chunk id: k8*16 + b
                uint k8 = c >> 4, b = c & 15u;
                hstage[k8 * 17u + b] = hin[k8 * 256u + bbase + b];
            }
        }
        __syncthreads();
        // h-path MFMAs from LDS
        #pragma unroll
        for (int it = 0; it < 16; ++it) {
            short8 a = hstage[((uint)it * 4u + quad) * 17u + m];
            acc0 = __builtin_amdgcn_mfma_f32_16x16x32_bf16(a, wH[it][0], acc0, 0, 0, 0);
            acc1 = __builtin_amdgcn_mfma_f32_16x16x32_bf16(a, wH[it][1], acc1, 0, 0, 0);
        }
        // gate tiles -> LDS for cross-wave combine
        #pragma unroll
        for (int r = 0; r < 4; ++r) {
            gtile[(q * 16u + quad * 4u + (uint)r) * 34u + m]        = acc0[r];
            gtile[(q * 16u + quad * 4u + (uint)r) * 34u + 16u + m] = acc1[r];
        }
        __syncthreads();
        // elementwise LSTM epilogue: 2 (b,u) elements per thread, c in registers
        {
            float ge[4][2];
            #pragma unroll
            for (int g = 0; g < 4; ++g) {
                floatx2 v = *(const floatx2*)&gtile[((uint)g * 16u + eb) * 34u + eu];
                ge[g][0] = v[0]; ge[g][1] = v[1];
            }
            float i0 = fsigmoid(ge[0][0] + vbi0), i1 = fsigmoid(ge[0][1] + vbi1);
            float f0 = fsigmoid(ge[1][0] + vbf0), f1 = fsigmoid(ge[1][1] + vbf1);
            float g0 = ftanh(ge[2][0] + vbg0),    g1 = ftanh(ge[2][1] + vbg1);
            float o0 = fsigmoid(ge[3][0] + vbo0), o1 = fsigmoid(ge[3][1] + vbo1);
            c0 = f0 * c0 + i0 * g0;
            c1 = f1 * c1 + i1 * g1;
            float hv0 = o0 * ftanh(c0);
            float hv1 = o1 * ftanh(c1);
            uint hpack = (uint)f2b(hv0) | ((uint)f2b(hv1) << 16);
            ushort* hout = (t & 1) ? h0b : h1b;   // buffer (t+1)&1
            ((uint*)hout)[hidx] = hpack;
            if (t == SEQT - 1) {
                floatx2 ov; ov[0] = hv0; ov[1] = hv1;
                *(floatx2*)&out[gb * HID + gu] = ov;
            }
        }
        __syncthreads();   // drains all waves' h stores to L2
        if (tid == 0) {
            __builtin_amdgcn_fence(__ATOMIC_RELEASE, "agent");   // wbl2: flush to coherence point
            __hip_atomic_store(&flags[blk], (uint)(t + 1),
                               __ATOMIC_RELAXED, __HIP_MEMORY_SCOPE_AGENT);
        }
        #pragma unroll
        for (int kx = 0; kx < 8; ++kx) xa[kx] = xn[kx];
    }
}

extern "C" void kernel_launch(void* const* d_in, const int* in_sizes, int n_in,
                              void* d_out, int out_size, void* d_ws, size_t ws_size,
                              hipStream_t stream)
{
    (void)in_sizes; (void)n_in; (void)out_size; (void)ws_size;

    const float* x   = (const float*)d_in[0];
    const float* wui = (const float*)d_in[1];
    const float* whi = (const float*)d_in[2];
    const float* bi  = (const float*)d_in[3];
    const float* wuf = (const float*)d_in[4];
    const float* whf = (const float*)d_in[5];
    const float* bfr = (const float*)d_in[6];
    const float* wug = (const float*)d_in[7];
    const float* whg = (const float*)d_in[8];
    const float* bg  = (const float*)d_in[9];
    const float* wuo = (const float*)d_in[10];
    const float* who = (const float*)d_in[11];
    const float* bo  = (const float*)d_in[12];

    char* ws = (char*)d_ws;
    ushort* hp0   = (ushort*)(ws);             // 256 KB  h ping
    ushort* hp1   = (ushort*)(ws + 262144);    // 256 KB  h pong
    uint*   flags = (uint*)(ws + 524288);      // 1 KB    per-block step flags
    ushort* whp   = (ushort*)(ws + 1048576);   // 2 MB    packed W_h bf16
    ushort* wup   = (ushort*)(ws + 3145728);   // 1 MB    packed W_u bf16
    ushort* xp    = (ushort*)(ws + 4194304);   // 64 MB   x bf16

    hipMemsetAsync(hp0, 0, 262144, stream);
    hipMemsetAsync(flags, 0, 4096, stream);
    pack_x<<<32768, 256, 0, stream>>>((const float4v*)x, xp);
    pack_weights<<<6144, 256, 0, stream>>>(whi, whf, whg, who,
                                           wui, wuf, wug, wuo, whp, wup);

    lstm_persist<<<256, 256, 0, stream>>>(
        (const short8*)xp, (const short8*)whp, (const short8*)wup,
        bi, bfr, bg, bo,
        hp0, hp1, flags, (float*)d_out);
}

// Round 4
// 2544.225 us; speedup vs baseline: 3.3953x; 3.3953x over previous
//
#include <hip/hip_runtime.h>
#include <stdint.h>

#define BATCH 256
#define SEQT  512
#define INSZ  256
#define HID   512

typedef __attribute__((ext_vector_type(8))) short short8;
typedef __attribute__((ext_vector_type(4))) float floatx4;
typedef __attribute__((ext_vector_type(2))) float floatx2;
typedef __attribute__((ext_vector_type(4))) float float4v;
typedef unsigned long long u64;

__device__ __forceinline__ ushort f2b(float f) {
    union { float f; uint i; } v; v.f = f;
    uint r = (v.i + 0x7FFFu + ((v.i >> 16) & 1u)) >> 16;
    return (ushort)r;
}
__device__ __forceinline__ float fsigmoid(float x) {
    float e = __builtin_amdgcn_exp2f(-1.44269504f * x);
    return __builtin_amdgcn_rcpf(1.0f + e);
}
__device__ __forceinline__ float ftanh(float x) {
    float e = __builtin_amdgcn_exp2f(-2.88539008f * x);
    return 2.0f * __builtin_amdgcn_rcpf(1.0f + e) - 1.0f;
}

// Convert x fp32 -> bf16, same [B][T][I] layout. 4 elements/thread.
__global__ __launch_bounds__(256) void pack_x(
    const float4v* __restrict__ x, ushort* __restrict__ xp)
{
    uint idx = blockIdx.x * 256u + threadIdx.x;
    float4v v = x[idx];
    ushort4 o;
    o.x = f2b(v[0]); o.y = f2b(v[1]); o.z = f2b(v[2]); o.w = f2b(v[3]);
    *(ushort4*)&xp[idx * 4u] = o;
}

// Pack the 8 fp32 weight matrices into bf16 MFMA B-fragment layout.
// Wh per gate q: [c16(32)][k8(64)][n(16)][j(8)]  value = W[k8*8+j][c16*16+n]
// Wu per gate q: [c16(32)][k8(32)][n(16)][j(8)]
__global__ __launch_bounds__(256) void pack_weights(
    const float* __restrict__ whi, const float* __restrict__ whf,
    const float* __restrict__ whg, const float* __restrict__ who,
    const float* __restrict__ wui, const float* __restrict__ wuf,
    const float* __restrict__ wug, const float* __restrict__ wuo,
    ushort* __restrict__ whp, ushort* __restrict__ wup)
{
    uint idx = blockIdx.x * 256u + threadIdx.x;
    if (idx < (1u << 20)) {
        uint n = idx & 15u, j = (idx >> 4) & 7u;
        uint k8 = (idx >> 7) & 63u, c16 = (idx >> 13) & 31u, q = idx >> 18;
        const float* w = (q == 0) ? whi : (q == 1) ? whf : (q == 2) ? whg : who;
        float v = w[(k8 * 8u + j) * HID + c16 * 16u + n];
        whp[(((q * 32u + c16) * 64u + k8) * 16u + n) * 8u + j] = f2b(v);
    } else {
        uint idx2 = idx - (1u << 20);
        if (idx2 < (1u << 19)) {
            uint n = idx2 & 15u, j = (idx2 >> 4) & 7u;
            uint k8 = (idx2 >> 7) & 31u, c16 = (idx2 >> 12) & 31u, q = idx2 >> 17;
            const float* w = (q == 0) ? wui : (q == 1) ? wuf : (q == 2) ? wug : wuo;
            float v = w[(k8 * 8u + j) * HID + c16 * 16u + n];
            wup[(((q * 32u + c16) * 32u + k8) * 16u + n) * 8u + j] = f2b(v);
        }
    }
}

// Persistent LSTM: 256 blocks, one launch for all 512 steps.
// Block (rg = batch-group of 16 rows, ug = unit-group of 32 units), wave = gate.
// Cross-block h exchange is fence-free: h and flags move via system-scope
// (sc0 sc1) relaxed atomics -> write-through to the coherence point, loads
// force L2 miss. No buffer_wbl2 / buffer_inv anywhere in the loop.
__global__ __launch_bounds__(256, 1) void lstm_persist(
    const short8* __restrict__ xp,   // [B][T][I] bf16 as short8
    const short8* __restrict__ whp,  // packed, q-stride 32768 (short8)
    const short8* __restrict__ wup,  // packed, q-stride 16384 (short8)
    const float* __restrict__ bi, const float* __restrict__ bfr,
    const float* __restrict__ bg, const float* __restrict__ bo,
    ushort* __restrict__ h0b,        // h ping  [k8(64)][b(256)] short8
    ushort* __restrict__ h1b,        // h pong
    uint*   __restrict__ flags,      // [256] steps completed per block
    float* __restrict__ out)
{
    __shared__ short8 hstage[1088];       // [k8(64)] stride 17 [b(16)]
    __shared__ float  gtile[4 * 16 * 34]; // [gate][b_local(16)][u_local pad 34]

    const uint blk = blockIdx.x;
    const uint rg = blk >> 4, ug = blk & 15u;
    const uint bbase = rg * 16u;
    const uint tid = threadIdx.x;
    const uint lane = tid & 63u;
    const uint q = tid >> 6;              // gate index = wave
    const uint m = lane & 15u, quad = lane >> 4;
    const uint b_row = bbase + m;

    // ---- weights -> registers (once) ----
    short8 wH[16][2];
    short8 wX[8][2];
    {
        const uint qh = q * 32768u, qx = q * 16384u;
        #pragma unroll
        for (int it = 0; it < 16; ++it) {
            uint k8 = (uint)it * 4u + quad;
            #pragma unroll
            for (int s = 0; s < 2; ++s) {
                uint c16 = ug * 2u + (uint)s;
                wH[it][s] = whp[qh + (c16 * 64u + k8) * 16u + m];
            }
        }
        #pragma unroll
        for (int kx = 0; kx < 8; ++kx) {
            #pragma unroll
            for (int s = 0; s < 2; ++s) {
                uint c16 = ug * 2u + (uint)s;
                wX[kx][s] = wup[qx + (c16 * 32u + (uint)kx * 4u + quad) * 16u + m];
            }
        }
    }

    // ---- epilogue ownership: 2 adjacent units x 1 row per thread ----
    const uint eb = tid & 15u;
    const uint eu = (tid >> 4) * 2u;
    const uint gb = bbase + eb;
    const uint gu = ug * 32u + eu;
    float c0 = 0.f, c1 = 0.f;
    const float vbi0 = bi[gu],  vbi1 = bi[gu + 1];
    const float vbf0 = bfr[gu], vbf1 = bfr[gu + 1];
    const float vbg0 = bg[gu],  vbg1 = bg[gu + 1];
    const float vbo0 = bo[gu],  vbo1 = bo[gu + 1];
    const uint hidx = (((gu >> 3) * 256u + gb) * 8u + (gu & 7u)) >> 1; // uint idx

    // ---- staging ownership: 64 B (8 x u64) per thread ----
    const uint sk8 = tid >> 2;            // k8 row 0..63
    const uint sqt = tid & 3u;            // quarter of the 16-row slice
    const uint ssrc = (sk8 * 256u + bbase) * 2u + sqt * 8u;  // u64 index

    // ---- x prefetch for t=0 ----
    short8 xa[8];
    #pragma unroll
    for (int kx = 0; kx < 8; ++kx)
        xa[kx] = xp[(b_row * SEQT + 0u) * 32u + (uint)kx * 4u + quad];

    const uint flagbase = rg * 16u;

    for (int t = 0; t < SEQT; ++t) {
        // prefetch x for t+1 (issue loads, let them fly through the spin)
        short8 xn[8];
        {
            uint tn = (t + 1 < SEQT) ? (uint)(t + 1) : (uint)t;
            #pragma unroll
            for (int kx = 0; kx < 8; ++kx)
                xn[kx] = xp[(b_row * SEQT + tn) * 32u + (uint)kx * 4u + quad];
        }
        // x-path MFMAs (independent of h)
        floatx4 acc0 = {}, acc1 = {};
        #pragma unroll
        for (int kx = 0; kx < 8; ++kx) {
            acc0 = __builtin_amdgcn_mfma_f32_16x16x32_bf16(xa[kx], wX[kx][0], acc0, 0, 0, 0);
            acc1 = __builtin_amdgcn_mfma_f32_16x16x32_bf16(xa[kx], wX[kx][1], acc1, 0, 0, 0);
        }
        // clique barrier: wait until all 16 peer blocks completed step t
        if (t > 0) {
            for (;;) {
                uint v = 0xFFFFFFFFu;
                if (lane < 16u)
                    v = __hip_atomic_load(&flags[flagbase + lane],
                                          __ATOMIC_RELAXED, __HIP_MEMORY_SCOPE_SYSTEM);
                if (__ballot(v < (uint)t) == 0ull) break;
                __builtin_amdgcn_s_sleep(1);
            }
            __asm__ __volatile__("" ::: "memory");
        }
        // stage this block's h slice (16 rows x 512 units = 16 KB) into LDS
        // via system-scope loads (force L2 miss -> fresh data from L3)
        {
            const u64* hin = (const u64*)((t & 1) ? h1b : h0b);
            u64 hv[8];
            #pragma unroll
            for (int i = 0; i < 8; ++i)
                hv[i] = __hip_atomic_load(&hin[ssrc + (uint)i],
                                          __ATOMIC_RELAXED, __HIP_MEMORY_SCOPE_SYSTEM);
            #pragma unroll
            for (int i = 0; i < 8; ++i) {
                uint b = (sqt * 8u + (uint)i) >> 1, half = (uint)i & 1u;
                ((u64*)&hstage[sk8 * 17u + b])[half] = hv[i];
            }
        }
        __syncthreads();
        // h-path MFMAs from LDS
        #pragma unroll
        for (int it = 0; it < 16; ++it) {
            short8 a = hstage[((uint)it * 4u + quad) * 17u + m];
            acc0 = __builtin_amdgcn_mfma_f32_16x16x32_bf16(a, wH[it][0], acc0, 0, 0, 0);
            acc1 = __builtin_amdgcn_mfma_f32_16x16x32_bf16(a, wH[it][1], acc1, 0, 0, 0);
        }
        // gate tiles -> LDS for cross-wave combine
        #pragma unroll
        for (int r = 0; r < 4; ++r) {
            gtile[(q * 16u + quad * 4u + (uint)r) * 34u + m]        = acc0[r];
            gtile[(q * 16u + quad * 4u + (uint)r) * 34u + 16u + m] = acc1[r];
        }
        __syncthreads();
        // elementwise LSTM epilogue: 2 (b,u) elements per thread, c in registers
        {
            float ge[4][2];
            #pragma unroll
            for (int g = 0; g < 4; ++g) {
                floatx2 v = *(const floatx2*)&gtile[((uint)g * 16u + eb) * 34u + eu];
                ge[g][0] = v[0]; ge[g][1] = v[1];
            }
            float i0 = fsigmoid(ge[0][0] + vbi0), i1 = fsigmoid(ge[0][1] + vbi1);
            float f0 = fsigmoid(ge[1][0] + vbf0), f1 = fsigmoid(ge[1][1] + vbf1);
            float g0 = ftanh(ge[2][0] + vbg0),    g1 = ftanh(ge[2][1] + vbg1);
            float o0 = fsigmoid(ge[3][0] + vbo0), o1 = fsigmoid(ge[3][1] + vbo1);
            c0 = f0 * c0 + i0 * g0;
            c1 = f1 * c1 + i1 * g1;
            float hv0 = o0 * ftanh(c0);
            float hv1 = o1 * ftanh(c1);
            uint hpack = (uint)f2b(hv0) | ((uint)f2b(hv1) << 16);
            uint* hout = (uint*)((t & 1) ? h0b : h1b);   // buffer (t+1)&1
            __hip_atomic_store(&hout[hidx], hpack,
                               __ATOMIC_RELAXED, __HIP_MEMORY_SCOPE_SYSTEM);
            if (t == SEQT - 1) {
                floatx2 ov; ov[0] = hv0; ov[1] = hv1;
                *(floatx2*)&out[gb * HID + gu] = ov;
            }
        }
        // each wave: wait for its h stores to reach the coherence point
        __asm__ __volatile__("s_waitcnt vmcnt(0)" ::: "memory");
        __syncthreads();   // all waves' stores acked before flag publish
        if (tid == 0)
            __hip_atomic_store(&flags[blk], (uint)(t + 1),
                               __ATOMIC_RELAXED, __HIP_MEMORY_SCOPE_SYSTEM);
        #pragma unroll
        for (int kx = 0; kx < 8; ++kx) xa[kx] = xn[kx];
    }
}

extern "C" void kernel_launch(void* const* d_in, const int* in_sizes, int n_in,
                              void* d_out, int out_size, void* d_ws, size_t ws_size,
                              hipStream_t stream)
{
    (void)in_sizes; (void)n_in; (void)out_size; (void)ws_size;

    const float* x   = (const float*)d_in[0];
    const float* wui = (const float*)d_in[1];
    const float* whi = (const float*)d_in[2];
    const float* bi  = (const float*)d_in[3];
    const float* wuf = (const float*)d_in[4];
    const float* whf = (const float*)d_in[5];
    const float* bfr = (const float*)d_in[6];
    const float* wug = (const float*)d_in[7];
    const float* whg = (const float*)d_in[8];
    const float* bg  = (const float*)d_in[9];
    const float* wuo = (const float*)d_in[10];
    const float* who = (const float*)d_in[11];
    const float* bo  = (const float*)d_in[12];

    char* ws = (char*)d_ws;
    ushort* hp0   = (ushort*)(ws);             // 256 KB  h ping
    ushort* hp1   = (ushort*)(ws + 262144);    // 256 KB  h pong
    uint*   flags = (uint*)(ws + 524288);      // 1 KB    per-block step flags
    ushort* whp   = (ushort*)(ws + 1048576);   // 2 MB    packed W_h bf16
    ushort* wup   = (ushort*)(ws + 3145728);   // 1 MB    packed W_u bf16
    ushort* xp    = (ushort*)(ws + 4194304);   // 64 MB   x bf16

    hipMemsetAsync(hp0, 0, 262144, stream);
    hipMemsetAsync(flags, 0, 4096, stream);
    pack_x<<<32768, 256, 0, stream>>>((const float4v*)x, xp);
    pack_weights<<<6144, 256, 0, stream>>>(whi, whf, whg, who,
                                           wui, wuf, wug, wuo, whp, wup);

    lstm_persist<<<256, 256, 0, stream>>>(
        (const short8*)xp, (const short8*)whp, (const short8*)wup,
        bi, bfr, bg, bo,
        hp0, hp1, flags, (float*)d_out);
}